// Round 1
// baseline (172.623 us; speedup 1.0000x reference)
//
#include <hip/hip_runtime.h>

// YOLO batched-NMS, N=8192, 80 classes, IoU>0.5.
// Exactness strategy: replicate reference fp32 arithmetic with _rn intrinsics
// (no FMA contraction) so every keep/suppress decision matches numpy bit-for-bit.

#define N 8192
#define NC 80
#define COLS 85
#define MAXK 2048   // per-class kept-box capacity (expected ~102/class)

// ---------------- Kernel A: per-row score, argmax class, global coord max ----
__global__ __launch_bounds__(256) void score_kernel(const float* __restrict__ X,
                                                    float* __restrict__ scores,
                                                    int* __restrict__ cat,
                                                    unsigned int* __restrict__ maxc) {
    int wave = threadIdx.x >> 6;
    int lane = threadIdx.x & 63;
    int row = blockIdx.x * 4 + wave;
    const float* rp = X + (size_t)row * COLS;

    // 80 class probs: lane covers j=lane, lanes 0..15 also j=64+lane
    float v1 = rp[5 + lane];
    float v2 = (lane < 16) ? rp[5 + 64 + lane] : -INFINITY;
    float bv; int bi;
    if (v2 > v1) { bv = v2; bi = lane + 64; } else { bv = v1; bi = lane; }  // tie -> smaller idx
    #pragma unroll
    for (int m = 32; m >= 1; m >>= 1) {
        float ov = __shfl_xor(bv, m, 64);
        int   oi = __shfl_xor(bi, m, 64);
        if (ov > bv || (ov == bv && oi < bi)) { bv = ov; bi = oi; }
    }
    // coord max over first 4 columns
    float c = (lane < 4) ? rp[lane] : 0.0f;
    #pragma unroll
    for (int m = 32; m >= 1; m >>= 1) c = fmaxf(c, __shfl_xor(c, m, 64));

    __shared__ float cmax[4];
    if (lane == 0) {
        scores[row] = __fmul_rn(rp[4], bv);   // obj * max_cls, fp32 RN
        cat[row] = bi;
        cmax[wave] = c;
    }
    __syncthreads();
    if (threadIdx.x == 0) {
        float m = fmaxf(fmaxf(cmax[0], cmax[1]), fmaxf(cmax[2], cmax[3]));
        atomicMax(maxc, __float_as_uint(m));  // coords >= 0, uint-bit order == float order
    }
}

// ---------------- Kernel B1: exact descending stable rank ------------------
__global__ __launch_bounds__(256) void rank_kernel(const float* __restrict__ scores,
                                                   int* __restrict__ rank) {
    __shared__ float sj[256];
    int t = threadIdx.x;
    int i = blockIdx.x * 256 + t;
    int jbase = blockIdx.y * 256;
    sj[t] = scores[jbase + t];
    __syncthreads();
    float si = scores[i];
    int cnt = 0;
    #pragma unroll 8
    for (int k = 0; k < 256; ++k) {
        float s = sj[k];
        int j = jbase + k;
        cnt += (s > si) || (s == si && j < i);   // stable argsort(-scores)
    }
    atomicAdd(&rank[i], cnt);
}

// ---------------- Kernel B2: scatter into sorted order, build offset boxes --
__global__ __launch_bounds__(256) void scatter_kernel(const float* __restrict__ X,
                                                      const int* __restrict__ cat,
                                                      const int* __restrict__ rank,
                                                      const unsigned int* __restrict__ maxc,
                                                      int* __restrict__ order,
                                                      int* __restrict__ scat,
                                                      float4* __restrict__ sbox,
                                                      float* __restrict__ sarea) {
    int i = blockIdx.x * 256 + threadIdx.x;
    int r = rank[i];
    order[r] = i;
    int c = cat[i];
    scat[r] = c;
    float F = __fadd_rn(__uint_as_float(*maxc), 1.0f);   // max_coord + 1.0
    float off = __fmul_rn((float)c, F);                  // cat * (max_coord+1)
    const float* rp = X + (size_t)i * COLS;
    float b0 = __fadd_rn(rp[0], off);
    float b1 = __fadd_rn(rp[1], off);
    float b2 = __fadd_rn(rp[2], off);
    float b3 = __fadd_rn(rp[3], off);
    sbox[r] = make_float4(b0, b1, b2, b3);
    sarea[r] = __fmul_rn(__fsub_rn(b2, b0), __fsub_rn(b3, b1));  // area on offset boxes (as ref)
}

// ---------------- Kernel C: per-class greedy NMS (one wave per class) -------
__global__ __launch_bounds__(64) void nms_kernel(const int* __restrict__ scat,
                                                 const float4* __restrict__ sbox,
                                                 const float* __restrict__ sarea,
                                                 float* __restrict__ keep) {
    __shared__ float4 kbox[MAXK];
    __shared__ float  karea[MAXK];
    int c = blockIdx.x;
    int lane = threadIdx.x;
    int K = 0;

    // prefetch chunk 0
    int    cc = scat[lane];
    float4 mb = sbox[lane];
    float  ma = sarea[lane];

    for (int base = 0; base < N; base += 64) {
        // prefetch next chunk
        int nc_ = 0; float4 nb = {}; float na = 0.0f;
        if (base + 64 < N) {
            nc_ = scat[base + 64 + lane];
            nb  = sbox[base + 64 + lane];
            na  = sarea[base + 64 + lane];
        }
        unsigned long long m = __ballot(cc == c);
        while (m) {
            int b = __builtin_ctzll(m);
            m &= m - 1;
            int r = base + b;
            // broadcast candidate box from lane b
            float bx = __shfl(mb.x, b, 64);
            float by = __shfl(mb.y, b, 64);
            float bz = __shfl(mb.z, b, 64);
            float bw = __shfl(mb.w, b, 64);
            float aj = __shfl(ma, b, 64);
            int sup = 0;
            for (int k = lane; k < K; k += 64) {
                float4 kb = kbox[k];
                float ltx = fmaxf(kb.x, bx), lty = fmaxf(kb.y, by);
                float rbx = fminf(kb.z, bz), rby = fminf(kb.w, bw);
                float wx = fmaxf(__fsub_rn(rbx, ltx), 0.0f);
                float wy = fmaxf(__fsub_rn(rby, lty), 0.0f);
                float inter = __fmul_rn(wx, wy);
                float denom = __fsub_rn(__fadd_rn(karea[k], aj), inter);
                float iou = __fdiv_rn(inter, denom);
                sup |= (iou > 0.5f) ? 1 : 0;
            }
            unsigned long long anysup = __ballot(sup != 0);
            if (anysup == 0ULL) {
                if (lane == 0) keep[r] = 1.0f;
                if (K < MAXK) {
                    if (lane == 0) { kbox[K] = make_float4(bx, by, bz, bw); karea[K] = aj; }
                    K++;
                    __syncthreads();   // single wave: just drains LDS write
                }
            } else {
                if (lane == 0) keep[r] = 0.0f;
            }
        }
        cc = nc_; mb = nb; ma = na;
    }
}

// ---------------- Kernel D: out[r] = X[order[r]] * keep[r] ------------------
__global__ __launch_bounds__(256) void out_kernel(const float* __restrict__ X,
                                                  const int* __restrict__ order,
                                                  const float* __restrict__ keep,
                                                  float* __restrict__ out) {
    int idx = blockIdx.x * 256 + threadIdx.x;   // grid sized exactly N*COLS
    int r = idx / COLS;
    int col = idx - r * COLS;
    out[idx] = __fmul_rn(X[(size_t)order[r] * COLS + col], keep[r]);
}

extern "C" void kernel_launch(void* const* d_in, const int* in_sizes, int n_in,
                              void* d_out, int out_size, void* d_ws, size_t ws_size,
                              hipStream_t stream) {
    const float* X = (const float*)d_in[0];
    float* out = (float*)d_out;
    char* ws = (char*)d_ws;

    // workspace layout (16B aligned chunks)
    int*          rank   = (int*)(ws + 0);            // 32768 B  (memset 0)
    unsigned int* maxc   = (unsigned int*)(ws + 32768); // 4 B    (memset 0)
    float*        scores = (float*)(ws + 49152);
    int*          cat    = (int*)(ws + 81920);
    int*          order  = (int*)(ws + 114688);
    int*          scat   = (int*)(ws + 147456);
    float*        sarea  = (float*)(ws + 180224);
    float*        keep   = (float*)(ws + 212992);
    float4*       sbox   = (float4*)(ws + 245760);    // 131072 B

    hipMemsetAsync(d_ws, 0, 32772, stream);

    score_kernel<<<N / 4, 256, 0, stream>>>(X, scores, cat, maxc);
    rank_kernel<<<dim3(N / 256, N / 256), 256, 0, stream>>>(scores, rank);
    scatter_kernel<<<N / 256, 256, 0, stream>>>(X, cat, rank, maxc, order, scat, sbox, sarea);
    nms_kernel<<<NC, 64, 0, stream>>>(scat, sbox, sarea, keep);
    out_kernel<<<(N * COLS) / 256, 256, 0, stream>>>(X, order, keep, out);
}